// Round 1
// baseline (189.151 us; speedup 1.0000x reference)
//
#include <hip/hip_runtime.h>
#include <cstdint>

typedef unsigned short u16;
typedef __attribute__((ext_vector_type(8))) short short8;
typedef __attribute__((ext_vector_type(4))) float f32x4;
typedef __attribute__((ext_vector_type(4))) unsigned short ushort4v;
typedef __attribute__((ext_vector_type(4))) unsigned int uint4v;

#if __has_builtin(__builtin_amdgcn_exp2f)
#define EXP2F(x) __builtin_amdgcn_exp2f(x)
#else
#define EXP2F(x) exp2f(x)
#endif

// fp32 -> bf16 bits, round-to-nearest-even
__device__ inline u16 f2bf(float f) {
  union { float f; unsigned u; } v; v.f = f;
  unsigned u = v.u;
  return (u16)((u + 0x7fffu + ((u >> 16) & 1u)) >> 16);
}

// bf16 bits -> fp32
__device__ inline float bf2f(u16 h) {
  union { unsigned u; float f; } v; v.u = ((unsigned)h) << 16;
  return v.f;
}

// pack two fp32 -> bf16x2 (a -> low); round-half-up (P>0 only, 1ulp vs RNE)
__device__ inline unsigned pk2bf_fast(float a, float b) {
  union { float f; unsigned u; } ua, ub; ua.f = a; ub.f = b;
  return __builtin_amdgcn_perm(ub.u + 0x8000u, ua.u + 0x8000u, 0x07060302u);
}

// async global -> LDS, 16B per lane (contiguous landing order only)
__device__ inline void gl2lds16(const void* g, void* l) {
  __builtin_amdgcn_global_load_lds(
      (const __attribute__((address_space(1))) unsigned int*)(unsigned long long)(uintptr_t)g,
      (__attribute__((address_space(3))) unsigned int*)(unsigned int)(uintptr_t)l,
      16, 0, 0);
}

// XOR chunk swizzle: within each 64-elem K-slice of a row, 16B chunk c of row
// r is stored at position c ^ (r & 7). gl2lds staging copies slices verbatim;
// fragment reads at chunk' = (kk*4+lg) ^ (l15&7) are phase-conflict-free.

// ---------------------------------------------------------------- cvt kernel
// wo is no longer converted: gemm_out consumes fp32 wo directly (split hi/lo).
__global__ __launch_bounds__(256) void cvt_kernel(
    const float* __restrict__ x,
    const float* __restrict__ wq, const float* __restrict__ wk,
    const float* __restrict__ wv,
    u16* __restrict__ xb, u16* __restrict__ wqb, u16* __restrict__ wkb,
    u16* __restrict__ wvb) {
  const int y = blockIdx.y;
  const int Q = 1 << 20;
  const float* src;
  u16* dst;
  if (y < 4)       { src = x + y * Q; dst = xb + y * Q; }
  else if (y == 4) { src = wq; dst = wqb; }
  else if (y == 5) { src = wk; dst = wkb; }
  else             { src = wv; dst = wvb; }
  const int i = (blockIdx.x * 256 + threadIdx.x) * 8;
  float4 a = *(const float4*)(src + i);
  float4 b = *(const float4*)(src + i + 4);
  short8 o;
  o[0] = (short)f2bf(a.x); o[1] = (short)f2bf(a.y);
  o[2] = (short)f2bf(a.z); o[3] = (short)f2bf(a.w);
  o[4] = (short)f2bf(b.x); o[5] = (short)f2bf(b.y);
  o[6] = (short)f2bf(b.z); o[7] = (short)f2bf(b.w);
  const int j = (i & ~63) | (((((i >> 3) & 7) ^ ((i >> 10) & 7))) << 3);
  *(short8*)(dst + j) = o;
}

// ------------------------------------------------------------ QKV projection
// Z-FUSED NT GEMM: x staged once feeds 3 B-panels, 48 MFMA/wave per k-iter.
// grid (16, 32) = 512 blocks, 80 KB LDS -> 2 blocks/CU. Double-buffered
// gl2lds, one barrier per K-iter.
// Q out: plain [B,NH,S,D], PRE-SCALED by log2(e)/8 (softmax fold).
// K out: [B,NH,S,D] chunk-swizzled by s&7.
// V out: V^T [B,NH,D,Sperm]; key slot within each 64-key block:
//   key = slice*32 + t*16 + quad*4 + r  ->  slot = slice*32 + quad*8 + t*4 + r
// (matches attn's P B-operand key order); chunk-swizzled by d&7.
__global__ __launch_bounds__(256, 2) void gemm_qkv(
    const u16* __restrict__ xb,
    const u16* __restrict__ wqb, const u16* __restrict__ wkb, const u16* __restrict__ wvb,
    const float* __restrict__ bq, const float* __restrict__ bk, const float* __restrict__ bv,
    u16* __restrict__ qo, u16* __restrict__ ko, u16* __restrict__ vto) {
  __shared__ u16 smem[40960];        // As[2][8192] | Bs[2][3][4096] = 80 KB
  u16* As = smem;                    // + p*8192
  u16* Bs = smem + 16384;            // + p*12288 + z*4096
  const int tid = threadIdx.x, lane = tid & 63;
  const int wid = tid >> 6;
  const int l15 = lane & 15, lg = lane >> 4;
  const int m0 = blockIdx.y * 128, n0 = blockIdx.x * 64;
  const int sw = ((l15 & 7) << 3);
  const u16* Wz[3] = {wqb, wkb, wvb};

  f32x4 acc[3][2][4] = {};

  // prologue: stage k0=0 into buffer 0
#pragma unroll
  for (int i = 0; i < 4; ++i) {
    int c = i * 256 + tid;
    gl2lds16(xb + (m0 + (c >> 3)) * 1024 + (c & 7) * 8, As + c * 8);
  }
#pragma unroll
  for (int z = 0; z < 3; ++z)
#pragma unroll
    for (int i = 0; i < 2; ++i) {
      int c = i * 256 + tid;
      gl2lds16(Wz[z] + (n0 + (c >> 3)) * 1024 + (c & 7) * 8, Bs + z * 4096 + c * 8);
    }

  for (int k0 = 0; k0 < 1024; k0 += 64) {
    const int p = (k0 >> 6) & 1;
    __syncthreads();  // drains vmcnt -> buf p ready
    if (k0 < 960) {
      u16* An = As + (1 - p) * 8192;
      u16* Bn = Bs + (1 - p) * 12288;
#pragma unroll
      for (int i = 0; i < 4; ++i) {
        int c = i * 256 + tid;
        gl2lds16(xb + (m0 + (c >> 3)) * 1024 + k0 + 64 + (c & 7) * 8, An + c * 8);
      }
#pragma unroll
      for (int z = 0; z < 3; ++z)
#pragma unroll
        for (int i = 0; i < 2; ++i) {
          int c = i * 256 + tid;
          gl2lds16(Wz[z] + (n0 + (c >> 3)) * 1024 + k0 + 64 + (c & 7) * 8, Bn + z * 4096 + c * 8);
        }
    }
    const u16* Ap = As + p * 8192;
    const u16* Bp = Bs + p * 12288;
#pragma unroll
    for (int kk = 0; kk < 2; ++kk) {
      short8 af[2], bf[3][4];
#pragma unroll
      for (int mb = 0; mb < 2; ++mb)
        af[mb] = *(const short8*)(Ap + (wid * 32 + mb * 16 + l15) * 64 + ((((kk * 4 + lg) << 3)) ^ sw));
#pragma unroll
      for (int z = 0; z < 3; ++z)
#pragma unroll
        for (int nb = 0; nb < 4; ++nb)
          bf[z][nb] = *(const short8*)(Bp + z * 4096 + (nb * 16 + l15) * 64 + ((((kk * 4 + lg) << 3)) ^ sw));
#pragma unroll
      for (int z = 0; z < 3; ++z)
#pragma unroll
        for (int mb = 0; mb < 2; ++mb)
#pragma unroll
          for (int nb = 0; nb < 4; ++nb)
            acc[z][mb][nb] = __builtin_amdgcn_mfma_f32_16x16x32_bf16(af[mb], bf[z][nb], acc[z][mb][nb], 0, 0, 0);
    }
  }

  const float cexp = 0.18033688011112042f;  // log2(e)/8 folded into Q

  // Q epilogue (plain layout, pre-scaled)
#pragma unroll
  for (int mb = 0; mb < 2; ++mb)
#pragma unroll
    for (int nb = 0; nb < 4; ++nb)
#pragma unroll
      for (int r = 0; r < 4; ++r) {
        int m = m0 + wid * 32 + mb * 16 + lg * 4 + r;  // b*2048 + s
        int n = n0 + nb * 16 + l15;                    // h*64 + d
        float v = (acc[0][mb][nb][r] + bq[n]) * cexp;
        int b = m >> 11, s = m & 2047, hh = n >> 6, d = n & 63;
        qo[((b * 16 + hh) * 2048 + s) * 64 + d] = f2bf(v);
      }

  // K epilogue (chunk-swizzled by s&7)
#pragma unroll
  for (int mb = 0; mb < 2; ++mb)
#pragma unroll
    for (int nb = 0; nb < 4; ++nb)
#pragma unroll
      for (int r = 0; r < 4; ++r) {
        int m = m0 + wid * 32 + mb * 16 + lg * 4 + r;
        int n = n0 + nb * 16 + l15;
        float v = acc[1][mb][nb][r] + bk[n];
        int b = m >> 11, s = m & 2047, hh = n >> 6, d = n & 63;
        int dcol = (((d >> 3) ^ (s & 7)) << 3) | (d & 7);
        ko[((b * 16 + hh) * 2048 + s) * 64 + dcol] = f2bf(v);
      }

  // V epilogue: wave-pair shared 64(d) x 72 transpose buffers, slot order per
  // the attn B-operand key permutation, then coalesced 16B global stores.
  __syncthreads();  // all waves done with As/Bs
  {
    u16* wbuf = smem + (wid >> 1) * 4608;
#pragma unroll
    for (int mb = 0; mb < 2; ++mb)
#pragma unroll
      for (int nb = 0; nb < 4; ++nb) {
        int n = n0 + nb * 16 + l15;
        float bn = bv[n];
        int dl = nb * 16 + l15;
#pragma unroll
        for (int r = 0; r < 4; ++r) {
          // key s64 = (wid&1)*32 + mb*16 + lg*4 + r  (slice=wid&1, t=mb, quad=lg)
          int sig = (wid & 1) * 32 + lg * 8 + mb * 4 + r;
          wbuf[dl * 72 + sig] = f2bf(acc[2][mb][nb][r] + bn);
        }
      }
    __syncthreads();  // cross-wave transpose complete
    int hh = n0 >> 6;
    int bb = m0 >> 11;
    int sbase = m0 & 2047;
#pragma unroll
    for (int i = 0; i < 4; ++i) {
      int idx = i * 256 + tid;           // 1024 chunks = 2 bufs x 64 x 8
      int p2 = idx >> 9, rem = idx & 511;
      int dl = rem >> 3, c = rem & 7;
      short8 vv = *(const short8*)(smem + p2 * 4608 + dl * 72 + c * 8);
      int cs = c ^ (dl & 7);             // chunk swizzle by d&7
      *(short8*)(vto + ((bb * 16 + hh) * 64 + dl) * 2048 + sbase + p2 * 64 + cs * 8) = vv;
    }
  }
}

// ---------------------------------------------------------------- attention
// TRANSPOSED dataflow: S^T = K·Q^T (A = K frag from LDS, B = Q regs; C col =
// q = l15, wave-private), P = exp2(S^T) stays in registers and is ALREADY the
// B-operand for O^T = V^T·P (A = V^T frag from LDS; key slots permuted to
// match C-layout key order). l via ones as A operand. P never touches LDS.
// Q pre-scaled by log2(e)/8; offset-free exp2.
// Epilogue now emits SPLIT-PRECISION ctx: hi = bf16(o), lo = bf16(o - hi),
// packed hi|lo<<16 through a u32 SP transpose (wave-private, in-order), then
// two coalesced swizzled 16B stores (ctx_hi, ctx_lo). Removes the ctx-store
// bf16 quantization from the out-projection error budget.
__global__ __launch_bounds__(256, 2) void attn_kernel(
    const u16* __restrict__ qg, const u16* __restrict__ kg,
    const u16* __restrict__ vtg, u16* __restrict__ ctxg, u16* __restrict__ ctxlg) {
  const int h = blockIdx.x, qt = blockIdx.y, b = blockIdx.z;
  const int bh = b * 16 + h;
  const u16* Qg = qg + (bh * 2048 + qt * 128) * 64;
  const u16* Kg = kg + bh * 2048 * 64;
  const u16* Vg = vtg + bh * 64 * 2048;

  __shared__ unsigned SP32[128 * 72];  // 36 KB: epilogue hi|lo transpose only
  __shared__ u16 KV[2][8192];          // [p][0:4096)=K tile, [p][4096:8192)=V^T

  const int tid = threadIdx.x, lane = tid & 63, wid = tid >> 6;
  const int l15 = lane & 15, lg = lane >> 4;
  const int row0 = wid * 32;     // this wave's 32 query rows
  const int sw = ((l15 & 7) << 3);

  // Q fragments direct from global (pre-scaled; reused all 32 kt).
  short8 qf[2][2];
#pragma unroll
  for (int qtile = 0; qtile < 2; ++qtile)
#pragma unroll
    for (int kk = 0; kk < 2; ++kk)
      qf[qtile][kk] = *(const short8*)(Qg + (row0 + qtile * 16 + l15) * 64 + kk * 32 + lg * 8);

  short8 ones8;
#pragma unroll
  for (int j = 0; j < 8; ++j) ones8[j] = (short)0x3F80;  // bf16 1.0

  // prologue: stage kt=0 into buffer 0
#pragma unroll
  for (int i = 0; i < 2; ++i) {
    int c = i * 256 + tid;
    gl2lds16(Kg + c * 8, &KV[0][c * 8]);
    gl2lds16(Vg + (c >> 3) * 2048 + (c & 7) * 8, &KV[0][4096 + c * 8]);
  }

  f32x4 acc[4][2] = {};   // O^T: [dtile][qtile], C col = q = l15, row = d
  f32x4 accl[2] = {};     // l:  [qtile], all rows identical = l[q=l15]

  for (int kt = 0; kt < 32; ++kt) {
    const int p = kt & 1;
    __syncthreads();  // drains vmcnt -> buf p ready
    if (kt < 31) {
#pragma unroll
      for (int i = 0; i < 2; ++i) {
        int c = i * 256 + tid;
        gl2lds16(Kg + (kt + 1) * 4096 + c * 8, &KV[1 - p][c * 8]);
        gl2lds16(Vg + (c >> 3) * 2048 + (kt + 1) * 64 + (c & 7) * 8, &KV[1 - p][4096 + c * 8]);
      }
    }
    const u16* Ks = &KV[p][0];
    const u16* Vts = &KV[p][4096];

    // S^T = K · Q^T : sc[ktile][qtile], C row = key = lg*4+r, col = q = l15
    f32x4 sc[4][2] = {};
#pragma unroll
    for (int kk = 0; kk < 2; ++kk) {
      short8 kf[4];
#pragma unroll
      for (int ktile = 0; ktile < 4; ++ktile)
        kf[ktile] = *(const short8*)(Ks + (ktile * 16 + l15) * 64 + ((((kk * 4 + lg) << 3)) ^ sw));
#pragma unroll
      for (int ktile = 0; ktile < 4; ++ktile)
#pragma unroll
        for (int qtile = 0; qtile < 2; ++qtile)
          sc[ktile][qtile] = __builtin_amdgcn_mfma_f32_16x16x32_bf16(kf[ktile], qf[qtile][kk], sc[ktile][qtile], 0, 0, 0);
    }

    // P = exp2(S^T) packed in-register into B-operand fragments.
    short8 pf[2][2];  // [slice][qtile]
#pragma unroll
    for (int sl = 0; sl < 2; ++sl)
#pragma unroll
      for (int qtile = 0; qtile < 2; ++qtile) {
        union { short8 s; unsigned u[4]; } pu;
        float a0 = EXP2F(sc[sl * 2][qtile][0]),     a1 = EXP2F(sc[sl * 2][qtile][1]);
        float a2 = EXP2F(sc[sl * 2][qtile][2]),     a3 = EXP2F(sc[sl * 2][qtile][3]);
        float b0 = EXP2F(sc[sl * 2 + 1][qtile][0]), b1 = EXP2F(sc[sl * 2 + 1][qtile][1]);
        float b2 = EXP2F(sc[sl * 2 + 1][qtile][2]), b3 = EXP2F(sc[sl * 2 + 1][qtile][3]);
        pu.u[0] = pk2bf_fast(a0, a1);
        pu.u[1] = pk2bf_fast(a2, a3);
        pu.u[2] = pk2bf_fast(b0, b1);
        pu.u[3] = pk2bf_fast(b2, b3);
        pf[sl][qtile] = pu.s;
      }

    // O^T += V^T · P ; l += 1 · P
#pragma unroll
    for (int sl = 0; sl < 2; ++sl) {
      short8 vf[4];
#pragma unroll
      for (int dtile = 0; dtile < 4; ++dtile)
        vf[dtile] = *(const short8*)(Vts + (dtile * 16 + l15) * 64 + ((((sl * 4 + lg) << 3)) ^ sw));
#pragma unroll
      for (int dtile = 0; dtile < 4; ++dtile)
#pragma unroll
        for (int qtile = 0; qtile < 2; ++qtile)
          acc[dtile][qtile] = __builtin_amdgcn_mfma_f32_16x16x32_bf16(vf[dtile], pf[sl][qtile], acc[dtile][qtile], 0, 0, 0);
#pragma unroll
      for (int qtile = 0; qtile < 2; ++qtile)
        accl[qtile] = __builtin_amdgcn_mfma_f32_16x16x32_bf16(ones8, pf[sl][qtile], accl[qtile], 0, 0, 0);
    }
  }

  // epilogue: normalize (lane owns q = l15 per qtile); o split hi/lo packed
  // into u32; transpose O^T -> O via SP32 (wave-private strips, same-wave
  // in-order); coalesced swizzled stores of hi and lo planes.
#pragma unroll
  for (int qtile = 0; qtile < 2; ++qtile) {
    float inv = 1.0f / accl[qtile][0];
#pragma unroll
    for (int dtile = 0; dtile < 4; ++dtile) {
      uint4v pk;
#pragma unroll
      for (int r = 0; r < 4; ++r) {
        float o = acc[dtile][qtile][r] * inv;   // d = dtile*16 + lg*4 + r
        u16 hi = f2bf(o);
        u16 lo = f2bf(o - bf2f(hi));
        pk[r] = (unsigned)hi | ((unsigned)lo << 16);
      }
      *(uint4v*)(SP32 + (row0 + qtile * 16 + l15) * 72 + dtile * 16 + lg * 4) = pk;
    }
  }
#pragma unroll
  for (int i = 0; i < 4; ++i) {
    int idx = i * 64 + lane;               // 256 chunks = 32 rows x 8
    int rl = idx >> 3, c = idx & 7;
    const unsigned* src = SP32 + (row0 + rl) * 72 + c * 8;
    uint4v w0 = *(const uint4v*)(src);
    uint4v w1 = *(const uint4v*)(src + 4);
    union { unsigned u[4]; short8 s; } H, L;
    H.u[0] = __builtin_amdgcn_perm(w0[1], w0[0], 0x05040100u);
    L.u[0] = __builtin_amdgcn_perm(w0[1], w0[0], 0x07060302u);
    H.u[1] = __builtin_amdgcn_perm(w0[3], w0[2], 0x05040100u);
    L.u[1] = __builtin_amdgcn_perm(w0[3], w0[2], 0x07060302u);
    H.u[2] = __builtin_amdgcn_perm(w1[1], w1[0], 0x05040100u);
    L.u[2] = __builtin_amdgcn_perm(w1[1], w1[0], 0x07060302u);
    H.u[3] = __builtin_amdgcn_perm(w1[3], w1[2], 0x05040100u);
    L.u[3] = __builtin_amdgcn_perm(w1[3], w1[2], 0x07060302u);
    int s = qt * 128 + row0 + rl;
    int cs = c ^ (s & 7);                  // chunk swizzle by s&7 for gemm_out
    long off = ((long)b * 2048 + s) * 1024 + h * 64 + cs * 8;
    *(short8*)(ctxg + off) = H.s;
    *(short8*)(ctxlg + off) = L.s;
  }
}

// ------------------------------------------------------------ out projection
// SPLIT-PRECISION: out[m,n] = sum_k (ctx_hi+ctx_lo)[m,k]*(wo_hi+wo_lo)[n,k]
// + bo[n], dropping the lo*lo term (~2^-16 rel). A panels (hi,lo bf16,
// chunk-swizzled) staged via gl2lds; B derived from the ORIGINAL fp32 wo:
// global->regs (prefetched one k-iter ahead), in-register split to hi/lo,
// ds_write swizzled panels — no bf16 wo workspace needed.
// 128x64 tile, grid (16,32) = 512 blocks, 48 KB LDS single-buffered ->
// 3 blocks/CU; 24 MFMA per 12 b128 ds_reads per kk.
__global__ __launch_bounds__(256, 3) void gemm_out(
    const u16* __restrict__ ch, const u16* __restrict__ cl,
    const float* __restrict__ wo, const float* __restrict__ bo,
    float* __restrict__ out) {
  __shared__ u16 smem[24576];  // Ah[8192] Al[8192] Bh[4096] Bl[4096] = 48 KB
  u16* Ah = smem;
  u16* Al = smem + 8192;
  u16* Bh = smem + 16384;
  u16* Bl = smem + 20480;
  const int tid = threadIdx.x, lane = tid & 63;
  const int wid = tid >> 6;
  const int l15 = lane & 15, lg = lane >> 4;
  const int m0 = blockIdx.y * 128, n0 = blockIdx.x * 64;
  const int sw = ((l15 & 7) << 3);
  const int brow = tid >> 2;           // wo row 0..63 within tile
  const int bk4 = (tid & 3) * 16;      // 16 consecutive k per thread

  f32x4 acc[2][4] = {};

  // prefetch wo regs for k0=0 (fp32, coalesced 64B/thread)
  float4 wr0[4], wr1[4];
#pragma unroll
  for (int j = 0; j < 4; ++j)
    wr0[j] = *(const float4*)(wo + (n0 + brow) * 1024 + bk4 + j * 4);

  for (int k0 = 0; k0 < 1024; k0 += 64) {
    __syncthreads();  // previous iter's LDS reads complete -> safe to overwrite
    // A staging (hi + lo), current k-slice; swizzle preserved verbatim
#pragma unroll
    for (int i = 0; i < 4; ++i) {
      int c = i * 256 + tid;
      gl2lds16(ch + (m0 + (c >> 3)) * 1024 + k0 + (c & 7) * 8, Ah + c * 8);
    }
#pragma unroll
    for (int i = 0; i < 4; ++i) {
      int c = i * 256 + tid;
      gl2lds16(cl + (m0 + (c >> 3)) * 1024 + k0 + (c & 7) * 8, Al + c * 8);
    }
    // prefetch wo regs for next iter (lands during compute below)
    if (k0 < 960) {
#pragma unroll
      for (int j = 0; j < 4; ++j)
        wr1[j] = *(const float4*)(wo + (n0 + brow) * 1024 + k0 + 64 + bk4 + j * 4);
    }
    // convert current wo regs -> Bh/Bl (each element converted once per block)
#pragma unroll
    for (int half = 0; half < 2; ++half) {
      short8 hh, ll;
#pragma unroll
      for (int q2 = 0; q2 < 2; ++q2) {
        float4 v = wr0[half * 2 + q2];
        float vv[4] = {v.x, v.y, v.z, v.w};
#pragma unroll
        for (int e = 0; e < 4; ++e) {
          u16 hi = f2bf(vv[e]);
          u16 lo = f2bf(vv[e] - bf2f(hi));
          hh[q2 * 4 + e] = (short)hi;
          ll[q2 * 4 + e] = (short)lo;
        }
      }
      int c = (tid & 3) * 2 + half;
      int pos = brow * 64 + ((c ^ (brow & 7)) << 3);
      *(short8*)(Bh + pos) = hh;
      *(short8*)(Bl + pos) = ll;
    }
    __syncthreads();  // gl2lds drained + B ds_writes visible

#pragma unroll
    for (int kk = 0; kk < 2; ++kk) {
      short8 ah[2], al[2], bh[4], bl[4];
#pragma unroll
      for (int mb = 0; mb < 2; ++mb) {
        int ro = (wid * 32 + mb * 16 + l15) * 64 + ((((kk * 4 + lg) << 3)) ^ sw);
        ah[mb] = *(const short8*)(Ah + ro);
        al[mb] = *(const short8*)(Al + ro);
      }
#pragma unroll
      for (int nb = 0; nb < 4; ++nb) {
        int ro = (nb * 16 + l15) * 64 + ((((kk * 4 + lg) << 3)) ^ sw);
        bh[nb] = *(const short8*)(Bh + ro);
        bl[nb] = *(const short8*)(Bl + ro);
      }
#pragma unroll
      for (int mb = 0; mb < 2; ++mb)
#pragma unroll
        for (int nb = 0; nb < 4; ++nb) {
          acc[mb][nb] = __builtin_amdgcn_mfma_f32_16x16x32_bf16(ah[mb], bh[nb], acc[mb][nb], 0, 0, 0);
          acc[mb][nb] = __builtin_amdgcn_mfma_f32_16x16x32_bf16(al[mb], bh[nb], acc[mb][nb], 0, 0, 0);
          acc[mb][nb] = __builtin_amdgcn_mfma_f32_16x16x32_bf16(ah[mb], bl[nb], acc[mb][nb], 0, 0, 0);
        }
    }
#pragma unroll
    for (int j = 0; j < 4; ++j) wr0[j] = wr1[j];
  }

#pragma unroll
  for (int mb = 0; mb < 2; ++mb)
#pragma unroll
    for (int nb = 0; nb < 4; ++nb)
#pragma unroll
      for (int r = 0; r < 4; ++r) {
        int m = m0 + wid * 32 + mb * 16 + lg * 4 + r;
        int n = n0 + nb * 16 + l15;
        out[m * 1024 + n] = acc[mb][nb][r] + bo[n];
      }
}

// --------------------------------------------------------------------- launch
extern "C" void kernel_launch(void* const* d_in, const int* in_sizes, int n_in,
                              void* d_out, int out_size, void* d_ws, size_t ws_size,
                              hipStream_t stream) {
  const float* x  = (const float*)d_in[0];
  const float* wq = (const float*)d_in[1];
  const float* bq = (const float*)d_in[2];
  const float* wk = (const float*)d_in[3];
  const float* bk = (const float*)d_in[4];
  const float* wv = (const float*)d_in[5];
  const float* bv = (const float*)d_in[6];
  const float* wo = (const float*)d_in[7];
  const float* bo = (const float*)d_in[8];

  // 23M u16 = 46 MiB (wob dropped; ctx_lo aliases xb, dead after gemm_qkv)
  if (ws_size < (size_t)23 * 1024 * 1024 * 2) return;
  u16* xb    = (u16*)d_ws;             // chunk-swizzled x (gemm_qkv input)
  u16* wqb   = xb  + (4u << 20);       // chunk-swizzled
  u16* wkb   = wqb + (1u << 20);
  u16* wvb   = wkb + (1u << 20);
  u16* qb    = wvb + (1u << 20);       // plain [B,NH,S,D], pre-scaled
  u16* kb    = qb  + (4u << 20);       // chunk-swizzled [B,NH,S,D]
  u16* vtb   = kb  + (4u << 20);       // V^T [B,NH,D,Sperm], chunk-swizzled
  u16* ctxb  = vtb + (4u << 20);       // ctx hi, chunk-swizzled [B,S,H]
  u16* ctxlb = xb;                     // ctx lo ALIASES xb (stream-ordered)

  cvt_kernel<<<dim3(512, 7, 1), 256, 0, stream>>>(x, wq, wk, wv, xb, wqb, wkb, wvb);
  gemm_qkv<<<dim3(16, 32, 1), 256, 0, stream>>>(xb, wqb, wkb, wvb, bq, bk, bv, qb, kb, vtb);
  attn_kernel<<<dim3(16, 16, 2), 256, 0, stream>>>(qb, kb, vtb, ctxb, ctxlb);
  gemm_out<<<dim3(16, 32, 1), 256, 0, stream>>>(ctxb, ctxlb, wo, bo, (float*)d_out);
}

// Round 5
// 172.312 us; speedup vs baseline: 1.0977x; 1.0977x over previous
//
#include <hip/hip_runtime.h>
#include <cstdint>

typedef unsigned short u16;
typedef __attribute__((ext_vector_type(8))) short short8;
typedef __attribute__((ext_vector_type(8))) _Float16 half8;
typedef __attribute__((ext_vector_type(2))) __fp16 fp16x2;   // cvt_pkrtz return type
typedef __attribute__((ext_vector_type(4))) float f32x4;
typedef __attribute__((ext_vector_type(4))) unsigned short ushort4v;

#if __has_builtin(__builtin_amdgcn_exp2f)
#define EXP2F(x) __builtin_amdgcn_exp2f(x)
#else
#define EXP2F(x) exp2f(x)
#endif

// Explicit drain of async global->LDS DMA (vmcnt) + LDS ops (lgkmcnt) BEFORE
// the barrier. The double-buffer handoff is only correct if every wave's
// outstanding global_load_lds has landed when it arrives at s_barrier; this
// makes that wait unconditional instead of relying on the compiler emitting
// it. Redundant when the compiler already does (s_waitcnt on drained
// counters retires immediately).
#define SYNC_DRAIN() do { \
  asm volatile("s_waitcnt vmcnt(0) lgkmcnt(0)" ::: "memory"); \
  __syncthreads(); \
} while (0)

// fp32 -> fp16 bits, round-to-nearest-even (v_cvt_f16_f32)
__device__ inline u16 f2h(float f) {
  union { _Float16 h; u16 u; } v;
  v.h = (_Float16)f;
  return v.u;
}

// async global -> LDS, 16B per lane (contiguous landing order only)
__device__ inline void gl2lds16(const void* g, void* l) {
  __builtin_amdgcn_global_load_lds(
      (const __attribute__((address_space(1))) unsigned int*)(unsigned long long)(uintptr_t)g,
      (__attribute__((address_space(3))) unsigned int*)(unsigned int)(uintptr_t)l,
      16, 0, 0);
}

// XOR chunk swizzle: within each 64-elem K-slice of a row, 16B chunk c of row
// r is stored at position c ^ (r & 7). gl2lds staging copies slices verbatim;
// fragment reads at chunk' = (kk*4+lg) ^ (l15&7) are phase-conflict-free.

// ---------------------------------------------------------------- cvt kernel
// Everything converts to FP16 (11-bit mantissa): 8x lower quantization error
// than bf16 at identical MFMA rate.
__global__ __launch_bounds__(256) void cvt_kernel(
    const float* __restrict__ x,
    const float* __restrict__ wq, const float* __restrict__ wk,
    const float* __restrict__ wv, const float* __restrict__ wo,
    u16* __restrict__ xb, u16* __restrict__ wqb, u16* __restrict__ wkb,
    u16* __restrict__ wvb, u16* __restrict__ wob) {
  const int y = blockIdx.y;
  const int Q = 1 << 20;
  const float* src;
  u16* dst;
  if (y < 4)       { src = x + y * Q; dst = xb + y * Q; }
  else if (y == 4) { src = wq; dst = wqb; }
  else if (y == 5) { src = wk; dst = wkb; }
  else if (y == 6) { src = wv; dst = wvb; }
  else             { src = wo; dst = wob; }
  const int i = (blockIdx.x * 256 + threadIdx.x) * 8;
  float4 a = *(const float4*)(src + i);
  float4 b = *(const float4*)(src + i + 4);
  short8 o;
  o[0] = (short)f2h(a.x); o[1] = (short)f2h(a.y);
  o[2] = (short)f2h(a.z); o[3] = (short)f2h(a.w);
  o[4] = (short)f2h(b.x); o[5] = (short)f2h(b.y);
  o[6] = (short)f2h(b.z); o[7] = (short)f2h(b.w);
  const int j = (i & ~63) | (((((i >> 3) & 7) ^ ((i >> 10) & 7))) << 3);
  *(short8*)(dst + j) = o;
}

// ------------------------------------------------------------ QKV projection
// Z-FUSED NT GEMM: x staged once feeds 3 B-panels, 48 MFMA/wave per k-iter.
// grid (16, 32) = 512 blocks, 80 KB LDS -> 2 blocks/CU. Double-buffered
// gl2lds, one barrier per K-iter. All operands FP16.
// Q out: plain [B,NH,S,D], PRE-SCALED by log2(e)/8 (softmax fold).
// K out: [B,NH,S,D] chunk-swizzled by s&7.
// V out: V^T [B,NH,D,Sperm]; key slot within each 64-key block:
//   key = slice*32 + t*16 + quad*4 + r  ->  slot = slice*32 + quad*8 + t*4 + r
// (matches attn's P B-operand key order); chunk-swizzled by d&7.
__global__ __launch_bounds__(256, 2) void gemm_qkv(
    const u16* __restrict__ xb,
    const u16* __restrict__ wqb, const u16* __restrict__ wkb, const u16* __restrict__ wvb,
    const float* __restrict__ bq, const float* __restrict__ bk, const float* __restrict__ bv,
    u16* __restrict__ qo, u16* __restrict__ ko, u16* __restrict__ vto) {
  __shared__ u16 smem[40960];        // As[2][8192] | Bs[2][3][4096] = 80 KB
  u16* As = smem;                    // + p*8192
  u16* Bs = smem + 16384;            // + p*12288 + z*4096
  const int tid = threadIdx.x, lane = tid & 63;
  const int wid = tid >> 6;
  const int l15 = lane & 15, lg = lane >> 4;
  const int m0 = blockIdx.y * 128, n0 = blockIdx.x * 64;
  const int sw = ((l15 & 7) << 3);
  const u16* Wz[3] = {wqb, wkb, wvb};

  f32x4 acc[3][2][4] = {};

  // prologue: stage k0=0 into buffer 0
#pragma unroll
  for (int i = 0; i < 4; ++i) {
    int c = i * 256 + tid;
    gl2lds16(xb + (m0 + (c >> 3)) * 1024 + (c & 7) * 8, As + c * 8);
  }
#pragma unroll
  for (int z = 0; z < 3; ++z)
#pragma unroll
    for (int i = 0; i < 2; ++i) {
      int c = i * 256 + tid;
      gl2lds16(Wz[z] + (n0 + (c >> 3)) * 1024 + (c & 7) * 8, Bs + z * 4096 + c * 8);
    }

  for (int k0 = 0; k0 < 1024; k0 += 64) {
    const int p = (k0 >> 6) & 1;
    SYNC_DRAIN();  // all waves' staging into buf p landed -> buf p ready
    if (k0 < 960) {
      u16* An = As + (1 - p) * 8192;
      u16* Bn = Bs + (1 - p) * 12288;
#pragma unroll
      for (int i = 0; i < 4; ++i) {
        int c = i * 256 + tid;
        gl2lds16(xb + (m0 + (c >> 3)) * 1024 + k0 + 64 + (c & 7) * 8, An + c * 8);
      }
#pragma unroll
      for (int z = 0; z < 3; ++z)
#pragma unroll
        for (int i = 0; i < 2; ++i) {
          int c = i * 256 + tid;
          gl2lds16(Wz[z] + (n0 + (c >> 3)) * 1024 + k0 + 64 + (c & 7) * 8, Bn + z * 4096 + c * 8);
        }
    }
    const u16* Ap = As + p * 8192;
    const u16* Bp = Bs + p * 12288;
#pragma unroll
    for (int kk = 0; kk < 2; ++kk) {
      half8 af[2], bf[3][4];
#pragma unroll
      for (int mb = 0; mb < 2; ++mb)
        af[mb] = *(const half8*)(Ap + (wid * 32 + mb * 16 + l15) * 64 + ((((kk * 4 + lg) << 3)) ^ sw));
#pragma unroll
      for (int z = 0; z < 3; ++z)
#pragma unroll
        for (int nb = 0; nb < 4; ++nb)
          bf[z][nb] = *(const half8*)(Bp + z * 4096 + (nb * 16 + l15) * 64 + ((((kk * 4 + lg) << 3)) ^ sw));
#pragma unroll
      for (int z = 0; z < 3; ++z)
#pragma unroll
        for (int mb = 0; mb < 2; ++mb)
#pragma unroll
          for (int nb = 0; nb < 4; ++nb)
            acc[z][mb][nb] = __builtin_amdgcn_mfma_f32_16x16x32_f16(af[mb], bf[z][nb], acc[z][mb][nb], 0, 0, 0);
    }
  }

  const float cexp = 0.18033688011112042f;  // log2(e)/8 folded into Q

  // Q epilogue (plain layout, pre-scaled)
#pragma unroll
  for (int mb = 0; mb < 2; ++mb)
#pragma unroll
    for (int nb = 0; nb < 4; ++nb)
#pragma unroll
      for (int r = 0; r < 4; ++r) {
        int m = m0 + wid * 32 + mb * 16 + lg * 4 + r;  // b*2048 + s
        int n = n0 + nb * 16 + l15;                    // h*64 + d
        float v = (acc[0][mb][nb][r] + bq[n]) * cexp;
        int b = m >> 11, s = m & 2047, hh = n >> 6, d = n & 63;
        qo[((b * 16 + hh) * 2048 + s) * 64 + d] = f2h(v);
      }

  // K epilogue (chunk-swizzled by s&7)
#pragma unroll
  for (int mb = 0; mb < 2; ++mb)
#pragma unroll
    for (int nb = 0; nb < 4; ++nb)
#pragma unroll
      for (int r = 0; r < 4; ++r) {
        int m = m0 + wid * 32 + mb * 16 + lg * 4 + r;
        int n = n0 + nb * 16 + l15;
        float v = acc[1][mb][nb][r] + bk[n];
        int b = m >> 11, s = m & 2047, hh = n >> 6, d = n & 63;
        int dcol = (((d >> 3) ^ (s & 7)) << 3) | (d & 7);
        ko[((b * 16 + hh) * 2048 + s) * 64 + dcol] = f2h(v);
      }

  // V epilogue: wave-pair shared 64(d) x 72 transpose buffers, slot order per
  // the attn B-operand key permutation, then coalesced 16B global stores.
  SYNC_DRAIN();  // all waves done with As/Bs (LDS reads + any DMA drained)
  {
    u16* wbuf = smem + (wid >> 1) * 4608;
#pragma unroll
    for (int mb = 0; mb < 2; ++mb)
#pragma unroll
      for (int nb = 0; nb < 4; ++nb) {
        int n = n0 + nb * 16 + l15;
        float bn = bv[n];
        int dl = nb * 16 + l15;
#pragma unroll
        for (int r = 0; r < 4; ++r) {
          // key s64 = (wid&1)*32 + mb*16 + lg*4 + r  (slice=wid&1, t=mb, quad=lg)
          int sig = (wid & 1) * 32 + lg * 8 + mb * 4 + r;
          wbuf[dl * 72 + sig] = f2h(acc[2][mb][nb][r] + bn);
        }
      }
    SYNC_DRAIN();  // cross-wave transpose complete
    int hh = n0 >> 6;
    int bb = m0 >> 11;
    int sbase = m0 & 2047;
#pragma unroll
    for (int i = 0; i < 4; ++i) {
      int idx = i * 256 + tid;           // 1024 chunks = 2 bufs x 64 x 8
      int p2 = idx >> 9, rem = idx & 511;
      int dl = rem >> 3, c = rem & 7;
      short8 vv = *(const short8*)(smem + p2 * 4608 + dl * 72 + c * 8);
      int cs = c ^ (dl & 7);             // chunk swizzle by d&7
      *(short8*)(vto + ((bb * 16 + hh) * 64 + dl) * 2048 + sbase + p2 * 64 + cs * 8) = vv;
    }
  }
}

// ---------------------------------------------------------------- attention
// TRANSPOSED dataflow: S^T = K·Q^T (A = K frag from LDS, B = Q regs; C col =
// q = l15, wave-private), P = exp2(S^T) stays in registers and is ALREADY the
// B-operand for O^T = V^T·P (A = V^T frag from LDS; key slots permuted to
// match C-layout key order). l via ones as A operand. P never touches LDS.
// Q pre-scaled by log2(e)/8; offset-free exp2. FP16 operands; P packed with
// single-instruction v_cvt_pkrtz_f16_f32 (RTZ bias cancels in O/l).
// Epilogue transposes O^T through SP for coalesced swizzled fp16 ctx stores,
// with a barrier between SP write and read (differently-typed LDS accesses).
// All buffer-handoff barriers use SYNC_DRAIN (explicit vmcnt drain).
__global__ __launch_bounds__(256, 2) void attn_kernel(
    const u16* __restrict__ qg, const u16* __restrict__ kg,
    const u16* __restrict__ vtg, u16* __restrict__ ctxg) {
  const int h = blockIdx.x, qt = blockIdx.y, b = blockIdx.z;
  const int bh = b * 16 + h;
  const u16* Qg = qg + (bh * 2048 + qt * 128) * 64;
  const u16* Kg = kg + bh * 2048 * 64;
  const u16* Vg = vtg + bh * 64 * 2048;

  __shared__ u16 SP[128 * 72];   // 18 KB: epilogue O-transpose only
  __shared__ u16 KV[2][8192];    // 32 KB: [p][0:4096)=K tile, [p][4096:8192)=V^T

  const int tid = threadIdx.x, lane = tid & 63, wid = tid >> 6;
  const int l15 = lane & 15, lg = lane >> 4;
  const int row0 = wid * 32;     // this wave's 32 query rows
  const int sw = ((l15 & 7) << 3);

  // Q fragments direct from global (pre-scaled; reused all 32 kt).
  // Used as B operand: (n = q = l15, k = d = lg*8.. + kk*32) — same layout.
  half8 qf[2][2];
#pragma unroll
  for (int qtile = 0; qtile < 2; ++qtile)
#pragma unroll
    for (int kk = 0; kk < 2; ++kk)
      qf[qtile][kk] = *(const half8*)(Qg + (row0 + qtile * 16 + l15) * 64 + kk * 32 + lg * 8);

  half8 ones8;
#pragma unroll
  for (int j = 0; j < 8; ++j) ones8[j] = (_Float16)1.0f;

  // prologue: stage kt=0 into buffer 0
#pragma unroll
  for (int i = 0; i < 2; ++i) {
    int c = i * 256 + tid;
    gl2lds16(Kg + c * 8, &KV[0][c * 8]);
    gl2lds16(Vg + (c >> 3) * 2048 + (c & 7) * 8, &KV[0][4096 + c * 8]);
  }

  f32x4 acc[4][2] = {};   // O^T: [dtile][qtile], C col = q = l15, row = d
  f32x4 accl[2] = {};     // l:  [qtile], all rows identical = l[q=l15]

  for (int kt = 0; kt < 32; ++kt) {
    const int p = kt & 1;
    SYNC_DRAIN();  // all waves' staging into buf p landed -> buf p ready
    if (kt < 31) {
#pragma unroll
      for (int i = 0; i < 2; ++i) {
        int c = i * 256 + tid;
        gl2lds16(Kg + (kt + 1) * 4096 + c * 8, &KV[1 - p][c * 8]);
        gl2lds16(Vg + (c >> 3) * 2048 + (kt + 1) * 64 + (c & 7) * 8, &KV[1 - p][4096 + c * 8]);
      }
    }
    const u16* Ks = &KV[p][0];
    const u16* Vts = &KV[p][4096];

    // S^T = K · Q^T : sc[ktile][qtile], C row = key = lg*4+r, col = q = l15
    f32x4 sc[4][2] = {};
#pragma unroll
    for (int kk = 0; kk < 2; ++kk) {
      half8 kf[4];
#pragma unroll
      for (int ktile = 0; ktile < 4; ++ktile)
        kf[ktile] = *(const half8*)(Ks + (ktile * 16 + l15) * 64 + ((((kk * 4 + lg) << 3)) ^ sw));
#pragma unroll
      for (int ktile = 0; ktile < 4; ++ktile)
#pragma unroll
        for (int qtile = 0; qtile < 2; ++qtile)
          sc[ktile][qtile] = __builtin_amdgcn_mfma_f32_16x16x32_f16(kf[ktile], qf[qtile][kk], sc[ktile][qtile], 0, 0, 0);
    }

    // P = exp2(S^T) packed in-register into B-operand fragments.
    // B element j of slice: key = slice*32 + (j>=4)*16 + quad*4 + (j&3);
    // V^T slots stored in exactly this order.
    half8 pf[2][2];  // [slice][qtile]
#pragma unroll
    for (int sl = 0; sl < 2; ++sl)
#pragma unroll
      for (int qtile = 0; qtile < 2; ++qtile) {
        union { half8 h; fp16x2 h2[4]; } pu;
        float a0 = EXP2F(sc[sl * 2][qtile][0]),     a1 = EXP2F(sc[sl * 2][qtile][1]);
        float a2 = EXP2F(sc[sl * 2][qtile][2]),     a3 = EXP2F(sc[sl * 2][qtile][3]);
        float b0 = EXP2F(sc[sl * 2 + 1][qtile][0]), b1 = EXP2F(sc[sl * 2 + 1][qtile][1]);
        float b2 = EXP2F(sc[sl * 2 + 1][qtile][2]), b3 = EXP2F(sc[sl * 2 + 1][qtile][3]);
        pu.h2[0] = __builtin_amdgcn_cvt_pkrtz(a0, a1);
        pu.h2[1] = __builtin_amdgcn_cvt_pkrtz(a2, a3);
        pu.h2[2] = __builtin_amdgcn_cvt_pkrtz(b0, b1);
        pu.h2[3] = __builtin_amdgcn_cvt_pkrtz(b2, b3);
        pf[sl][qtile] = pu.h;
      }

    // O^T += V^T · P ; l += 1 · P
#pragma unroll
    for (int sl = 0; sl < 2; ++sl) {
      half8 vf[4];
#pragma unroll
      for (int dtile = 0; dtile < 4; ++dtile)
        vf[dtile] = *(const half8*)(Vts + (dtile * 16 + l15) * 64 + ((((sl * 4 + lg) << 3)) ^ sw));
#pragma unroll
      for (int dtile = 0; dtile < 4; ++dtile)
#pragma unroll
        for (int qtile = 0; qtile < 2; ++qtile)
          acc[dtile][qtile] = __builtin_amdgcn_mfma_f32_16x16x32_f16(vf[dtile], pf[sl][qtile], acc[dtile][qtile], 0, 0, 0);
#pragma unroll
      for (int qtile = 0; qtile < 2; ++qtile)
        accl[qtile] = __builtin_amdgcn_mfma_f32_16x16x32_f16(ones8, pf[sl][qtile], accl[qtile], 0, 0, 0);
    }
  }

  // epilogue: normalize (lane owns q = l15 per qtile), transpose O^T -> O via
  // SP, then coalesced swizzled fp16 stores to ctx[b, s, h*64+d].
#pragma unroll
  for (int qtile = 0; qtile < 2; ++qtile) {
    float inv = 1.0f / accl[qtile][0];
#pragma unroll
    for (int dtile = 0; dtile < 4; ++dtile) {
      ushort4v pk;
#pragma unroll
      for (int r = 0; r < 4; ++r)
        pk[r] = f2h(acc[dtile][qtile][r] * inv);   // d = dtile*16 + lg*4 + r
      *(ushort4v*)(SP + (row0 + qtile * 16 + l15) * 72 + dtile * 16 + lg * 4) = pk;
    }
  }
  SYNC_DRAIN();  // SP writes must land before differently-typed reads
#pragma unroll
  for (int i = 0; i < 4; ++i) {
    int idx = i * 64 + lane;               // 256 chunks = 32 rows x 8
    int rl = idx >> 3, c = idx & 7;
    short8 vv = *(const short8*)(SP + (row0 + rl) * 72 + c * 8);
    int s = qt * 128 + row0 + rl;
    int cs = c ^ (s & 7);                  // chunk swizzle by s&7 for gemm_out
    *(short8*)(ctxg + ((long)b * 2048 + s) * 1024 + h * 64 + cs * 8) = vv;
  }
}

// ------------------------------------------------------------ out projection
// out[m,n] = sum_k ctx[m,k]*Wo[n,k] + bo[n], fp32 out, FP16 operands.
// 64x64 tiles, grid (16,64) = 1024 blocks, 32 KB LDS -> 4 blocks/CU.
__global__ __launch_bounds__(256) void gemm_out(
    const u16* __restrict__ cb, const u16* __restrict__ wob,
    const float* __restrict__ bo, float* __restrict__ out) {
  __shared__ u16 smem[16384];  // As[2][4096] | Bs[2][4096] = 32 KB
  u16* As = smem;
  u16* Bs = smem + 8192;
  const int tid = threadIdx.x, lane = tid & 63;
  const int wid = tid >> 6;
  const int l15 = lane & 15, lg = lane >> 4;
  const int m0 = blockIdx.y * 64, n0 = blockIdx.x * 64;
  const int sw = ((l15 & 7) << 3);

  f32x4 acc[4] = {};

#pragma unroll
  for (int i = 0; i < 2; ++i) {
    int c = i * 256 + tid;
    gl2lds16(cb  + (m0 + (c >> 3)) * 1024 + (c & 7) * 8, As + c * 8);
    gl2lds16(wob + (n0 + (c >> 3)) * 1024 + (c & 7) * 8, Bs + c * 8);
  }

  for (int k0 = 0; k0 < 1024; k0 += 64) {
    const int p = (k0 >> 6) & 1;
    SYNC_DRAIN();  // all waves' staging into buf p landed -> buf p ready
    if (k0 < 960) {
      u16* An = As + (1 - p) * 4096;
      u16* Bn = Bs + (1 - p) * 4096;
#pragma unroll
      for (int i = 0; i < 2; ++i) {
        int c = i * 256 + tid;
        gl2lds16(cb  + (m0 + (c >> 3)) * 1024 + k0 + 64 + (c & 7) * 8, An + c * 8);
        gl2lds16(wob + (n0 + (c >> 3)) * 1024 + k0 + 64 + (c & 7) * 8, Bn + c * 8);
      }
    }
    const u16* Ap = As + p * 4096;
    const u16* Bp = Bs + p * 4096;
#pragma unroll
    for (int kk = 0; kk < 2; ++kk) {
      half8 af, bf[4];
      af = *(const half8*)(Ap + (wid * 16 + l15) * 64 + ((((kk * 4 + lg) << 3)) ^ sw));
#pragma unroll
      for (int nb = 0; nb < 4; ++nb)
        bf[nb] = *(const half8*)(Bp + (nb * 16 + l15) * 64 + ((((kk * 4 + lg) << 3)) ^ sw));
#pragma unroll
      for (int nb = 0; nb < 4; ++nb)
        acc[nb] = __builtin_amdgcn_mfma_f32_16x16x32_f16(af, bf[nb], acc[nb], 0, 0, 0);
    }
  }

#pragma unroll
  for (int nb = 0; nb < 4; ++nb)
#pragma unroll
    for (int r = 0; r < 4; ++r) {
      int m = m0 + wid * 16 + lg * 4 + r;
      int n = n0 + nb * 16 + l15;
      out[m * 1024 + n] = acc[nb][r] + bo[n];
    }
}

// --------------------------------------------------------------------- launch
extern "C" void kernel_launch(void* const* d_in, const int* in_sizes, int n_in,
                              void* d_out, int out_size, void* d_ws, size_t ws_size,
                              hipStream_t stream) {
  const float* x  = (const float*)d_in[0];
  const float* wq = (const float*)d_in[1];
  const float* bq = (const float*)d_in[2];
  const float* wk = (const float*)d_in[3];
  const float* bk = (const float*)d_in[4];
  const float* wv = (const float*)d_in[5];
  const float* bv = (const float*)d_in[6];
  const float* wo = (const float*)d_in[7];
  const float* bo = (const float*)d_in[8];

  if (ws_size < (size_t)24 * 1024 * 1024 * 2) return;
  u16* xb   = (u16*)d_ws;              // chunk-swizzled fp16
  u16* wqb  = xb  + (4u << 20);        // chunk-swizzled fp16
  u16* wkb  = wqb + (1u << 20);
  u16* wvb  = wkb + (1u << 20);
  u16* wob  = wvb + (1u << 20);
  u16* qb   = wob + (1u << 20);        // plain [B,NH,S,D], pre-scaled fp16
  u16* kb   = qb  + (4u << 20);        // chunk-swizzled [B,NH,S,D] fp16
  u16* vtb  = kb  + (4u << 20);        // V^T [B,NH,D,Sperm], chunk-swizzled fp16
  u16* ctxb = vtb + (4u << 20);        // chunk-swizzled [B,S,H] fp16

  cvt_kernel<<<dim3(512, 8, 1), 256, 0, stream>>>(x, wq, wk, wv, wo, xb, wqb, wkb, wvb, wob);
  gemm_qkv<<<dim3(16, 32, 1), 256, 0, stream>>>(xb, wqb, wkb, wvb, bq, bk, bv, qb, kb, vtb);
  attn_kernel<<<dim3(16, 16, 2), 256, 0, stream>>>(qb, kb, vtb, ctxb);
  gemm_out<<<dim3(16, 64, 1), 256, 0, stream>>>(ctxb, wob, bo, (float*)d_out);
}